// Round 12
// baseline (1521.752 us; speedup 1.0000x reference)
//
#include <hip/hip_runtime.h>
#include <math.h>
#include <stdint.h>

namespace {
constexpr int INN   = 512;          // visible rows: act[:512] == x always
constexpr int LAY   = 2048;
constexpr int DYN   = LAY - INN;    // 1536 dynamic elements act[512..2048)
constexpr int NITER = 512;
constexpr int NBLK  = 64;
constexpr int TPB   = 256;          // 4 waves
constexpr int WVS   = TPB / 64;     // 4
constexpr int RPW   = 6;            // rows per wave
constexpr int RPB   = WVS * RPW;    // 24 rows/block; 64*24 = 1536
constexpr int KC    = DYN / 64;     // 24 dynamic k-chunks per lane
constexpr int KX    = INN / 64;     // 8 x-col k-chunks (precomputed)
constexpr int EPT   = DYN / TPB;    // 6 polled elements per thread
constexpr float EPS = 1e-12f;

typedef uint32_t u32x4 __attribute__((ext_vector_type(4)));

__device__ __forceinline__ uint64_t packtag(float v, uint32_t tag) {
  union { float f; uint32_t u; } c; c.f = v;
  return (uint64_t)c.u | ((uint64_t)tag << 32);
}
__device__ __forceinline__ float f_of(uint32_t u) {
  union { uint32_t u; float f; } c; c.u = u; return c.f;
}
// Proven store medium (R2..R10, absmax 0.0): agent-scope UC, served at MALL.
__device__ __forceinline__ void ag_store64(uint64_t* p, uint64_t v) {
  __hip_atomic_store(p, v, __ATOMIC_RELAXED, __HIP_MEMORY_SCOPE_AGENT);
}
// Poll read: 3x16B UC loads (sc0 sc1 = bypass L1+L2, same path as the
// agent atomics) over the thread's 48 contiguous bytes. Tags self-validate
// per 8B word; a single dwordx4 cannot tear an aligned 8B half.
__device__ __forceinline__ void poll3x16(const uint64_t* p,
                                         u32x4& a, u32x4& b, u32x4& c) {
  asm volatile(
      "global_load_dwordx4 %0, %3, off sc0 sc1\n\t"
      "global_load_dwordx4 %1, %3, off offset:16 sc0 sc1\n\t"
      "global_load_dwordx4 %2, %3, off offset:32 sc0 sc1\n\t"
      "s_waitcnt vmcnt(0)"
      : "=&v"(a), "=&v"(b), "=&v"(c)
      : "v"(p)
      : "memory");
}

// R10 champion (1335 us, absmax 0.0) + poll-side transaction coalescing:
// consumer thread tid now owns elements [6*tid, 6*tid+6) (contiguous 48B)
// and polls them with 3 coalesced 16B UC loads instead of 6 strided 8B
// loads — the exact mechanism (transaction coalescing) that produced R10's
// -27% on the store side. Producer side and buffer ordering unchanged.
// Protocol: tagged (value,iter) 8-byte words; a block stores tag t+1 only
// after block-wide consumption of tag t (__syncthreads between poll and
// store), so tag t+2 stores (which clobber t) imply every block consumed t.
__global__ __launch_bounds__(TPB) void bm_tag(
    const float* __restrict__ x, const float* __restrict__ W,
    uint64_t* __restrict__ buf0, uint64_t* __restrict__ buf1,
    float* __restrict__ out) {
  __shared__ float s_act[DYN];
  __shared__ float s_red[WVS];
  const int tid = threadIdx.x;
  const int wv  = tid >> 6;
  const int ln  = tid & 63;
  const int blk = blockIdx.x;
  const int r0  = INN + blk * RPB + wv * RPW;   // this wave's 6 rows
  const int e0  = EPT * tid;                    // my 6 contiguous elements

  // ---- one-time: W[r,512:2048] into registers (6x24 = 144 VGPR) ----
  float w[RPW][KC];
  const float* __restrict__ Wr = W + (size_t)r0 * LAY;
#pragma unroll
  for (int r = 0; r < RPW; ++r)
#pragma unroll
    for (int i = 0; i < KC; ++i)
      w[r][i] = Wr[(size_t)r * LAY + INN + ln + 64 * i];

  // ---- one-time: c_r = W[r,:512]@x (fully reduced; added AFTER lane-reduce) ----
  float c[RPW];
  {
    float xv[KX];
#pragma unroll
    for (int i = 0; i < KX; ++i) xv[i] = x[ln + 64 * i];
#pragma unroll
    for (int r = 0; r < RPW; ++r) {
      float cc = 0.f;
#pragma unroll
      for (int i = 0; i < KX; ++i)
        cc = fmaf(Wr[(size_t)r * LAY + ln + 64 * i], xv[i], cc);
#pragma unroll
      for (int o = 1; o < 64; o <<= 1) cc += __shfl_xor(cc, o, 64);
      c[r] = cc;
    }
  }

  // ---- bootstrap: act(1) = relu(c_r), tag 1 -> buf1; lane r stores row r
  //      (48B contiguous per wave -> coalesced, the R10 win) ----
  {
    float cv = c[0];
    cv = (ln == 1) ? c[1] : cv;
    cv = (ln == 2) ? c[2] : cv;
    cv = (ln == 3) ? c[3] : cv;
    cv = (ln == 4) ? c[4] : cv;
    cv = (ln == 5) ? c[5] : cv;
    if (ln < RPW)
      ag_store64(&buf1[r0 - INN + ln], packtag(fmaxf(cv, 0.f), 1u));
  }

  float myv[EPT];
  float inv = 0.f;
  for (int t = 1;; ++t) {
    if (t == NITER && blk != 0) return;   // non-0 blocks already stored tag 512
    uint64_t* rb = (t & 1) ? buf1 : buf0;

    // ---- poll act(t): 3 coalesced 16B UC loads per pass ----
    u32x4 qa, qb, qc;
    for (;;) {
      poll3x16(rb + e0, qa, qb, qc);
      const uint32_t tt = (uint32_t)t;
      bool ok = (qa.y == tt) & (qa.w == tt) & (qb.y == tt) &
                (qb.w == tt) & (qc.y == tt) & (qc.w == tt);
      if (ok) break;
    }
    myv[0] = f_of(qa.x); myv[1] = f_of(qa.z);
    myv[2] = f_of(qb.x); myv[3] = f_of(qb.z);
    myv[4] = f_of(qc.x); myv[5] = f_of(qc.z);

    // ---- stage to LDS (contiguous 24B/thread) + hidden sum-of-squares ----
    {
      float2* s2 = (float2*)s_act;
      s2[3 * tid]     = make_float2(myv[0], myv[1]);
      s2[3 * tid + 1] = make_float2(myv[2], myv[3]);
      s2[3 * tid + 2] = make_float2(myv[4], myv[5]);
    }
    float ss = 0.f;
#pragma unroll
    for (int j = 0; j < EPT; ++j)
      if (e0 + j >= 512) ss = fmaf(myv[j], myv[j], ss);   // hidden <=> dyn e>=512
#pragma unroll
    for (int o = 1; o < 64; o <<= 1) ss += __shfl_xor(ss, o, 64);
    if (ln == 0) s_red[wv] = ss;
    __syncthreads();                      // poll consumed block-wide; LDS ready
    inv = 1.0f / fmaxf(sqrtf(s_red[0] + s_red[1] + s_red[2] + s_red[3]), EPS);

    if (t == NITER) break;                // only blk 0 reaches

    // ---- matvec: y = relu(c + W[:,y-region]@a + inv * W[:,hidden]@h) ----
    float aa[RPW], bb[RPW];
#pragma unroll
    for (int r = 0; r < RPW; ++r) { aa[r] = 0.f; bb[r] = 0.f; }
#pragma unroll
    for (int i = 0; i < 8; ++i) {         // dyn cols [0,512): y-region
      const float a = s_act[ln + 64 * i];
#pragma unroll
      for (int r = 0; r < RPW; ++r) aa[r] = fmaf(w[r][i], a, aa[r]);
    }
#pragma unroll
    for (int i = 8; i < KC; ++i) {        // dyn cols [512,1536): hidden
      const float a = s_act[ln + 64 * i];
#pragma unroll
      for (int r = 0; r < RPW; ++r) bb[r] = fmaf(w[r][i], a, bb[r]);
    }
    float y[RPW];
#pragma unroll
    for (int r = 0; r < RPW; ++r) y[r] = fmaf(inv, bb[r], aa[r]);
#pragma unroll
    for (int o = 1; o < 64; o <<= 1) {
#pragma unroll
      for (int r = 0; r < RPW; ++r) y[r] += __shfl_xor(y[r], o, 64);
    }
#pragma unroll
    for (int r = 0; r < RPW; ++r) y[r] = fmaxf(y[r] + c[r], 0.f);  // c AFTER reduce
    __syncthreads();                      // WAR: LDS + buffer reads done

    // ---- publish act(t+1): lane r stores row r (coalesced 48B/wave) ----
    {
      float yv = y[0];
      yv = (ln == 1) ? y[1] : yv;
      yv = (ln == 2) ? y[2] : yv;
      yv = (ln == 3) ? y[3] : yv;
      yv = (ln == 4) ? y[4] : yv;
      yv = (ln == 5) ? y[5] : yv;
      if (ln < RPW) {
        uint64_t* wbuf = ((t + 1) & 1) ? buf1 : buf0;
        ag_store64(&wbuf[r0 - INN + ln], packtag(yv, (uint32_t)(t + 1)));
      }
    }
  }

  // ---- blk 0: final output (hidden part normalized) ----
  out[tid]       = x[tid];
  out[tid + TPB] = x[tid + TPB];
#pragma unroll
  for (int j = 0; j < EPT; ++j) {
    const int e = e0 + j;
    out[INN + e] = (e < 512) ? myv[j] : myv[j] * inv;
  }
}
} // namespace

extern "C" void kernel_launch(void* const* d_in, const int* in_sizes, int n_in,
                              void* d_out, int out_size, void* d_ws, size_t ws_size,
                              hipStream_t stream) {
  const float* x = (const float*)d_in[0];
  // d_in[1] (y) only enters the reference as zeros_like -> unused.
  const float* W = (const float*)d_in[2];
  float* out = (float*)d_out;

  uint64_t* buf0 = (uint64_t*)d_ws;
  uint64_t* buf1 = buf0 + DYN;

  // Invalidate stale tags (0xFFFFFFFF matches no t in 1..512) — needed on the
  // first call and between graph replays (harness does not re-poison d_ws).
  hipMemsetAsync(d_ws, 0xFF, (size_t)2 * DYN * sizeof(uint64_t), stream);

  bm_tag<<<dim3(NBLK), dim3(TPB), 0, stream>>>(x, W, buf0, buf1, out);
}

// Round 13
// 1299.943 us; speedup vs baseline: 1.1706x; 1.1706x over previous
//
#include <hip/hip_runtime.h>
#include <math.h>
#include <stdint.h>

namespace {
constexpr int INN   = 512;          // visible rows: act[:512] == x always
constexpr int LAY   = 2048;
constexpr int DYN   = LAY - INN;    // 1536 dynamic elements act[512..2048)
constexpr int NITER = 512;
constexpr int NBLK  = 64;
constexpr int TPB   = 256;          // 4 waves
constexpr int WVS   = TPB / 64;     // 4
constexpr int RPW   = 6;            // rows per wave
constexpr int RPB   = WVS * RPW;    // 24 rows/block; 64*24 = 1536
constexpr int KC    = DYN / 64;     // 24 dynamic k-chunks per lane
constexpr int KX    = INN / 64;     // 8 x-col k-chunks (precomputed)
constexpr int EPT   = DYN / TPB;    // 6 polled elements per thread
constexpr float EPS = 1e-12f;

__device__ __forceinline__ uint64_t packtag(float v, uint32_t tag) {
  union { float f; uint32_t u; } c; c.f = v;
  return (uint64_t)c.u | ((uint64_t)tag << 32);
}
__device__ __forceinline__ float val_of(uint64_t p) {
  union { uint32_t u; float f; } c; c.u = (uint32_t)p; return c.f;
}
// Proven medium (R2..R10, absmax 0.0): agent-scope UC ops, served at MALL,
// cross-XCD coherent, no fences needed.
__device__ __forceinline__ void ag_store64(uint64_t* p, uint64_t v) {
  __hip_atomic_store(p, v, __ATOMIC_RELAXED, __HIP_MEMORY_SCOPE_AGENT);
}
__device__ __forceinline__ uint64_t ag_load64(const uint64_t* p) {
  return __hip_atomic_load(p, __ATOMIC_RELAXED, __HIP_MEMORY_SCOPE_AGENT);
}

// R10 champion (1335 us, absmax 0.0; strided poll layout restored after
// R11's coalescing regression) + one change: the per-wave publish of
// act(t+1) moved BEFORE the WAR __syncthreads (B). Safety re-derivation:
// my completed poll of tag t => every block stored tag t => every block
// passed its sync-A of iter t-1 => every block consumed tag t-1 => my
// stores into parity (t+1)&1 (clobbering tag t-1) are safe as soon as my
// y is final — sync B is only needed for the s_act WAR, and stays.
__global__ __launch_bounds__(TPB) void bm_tag(
    const float* __restrict__ x, const float* __restrict__ W,
    uint64_t* __restrict__ buf0, uint64_t* __restrict__ buf1,
    float* __restrict__ out) {
  __shared__ float s_act[DYN];
  __shared__ float s_red[WVS];
  const int tid = threadIdx.x;
  const int wv  = tid >> 6;
  const int ln  = tid & 63;
  const int blk = blockIdx.x;
  const int r0  = INN + blk * RPB + wv * RPW;   // this wave's 6 rows

  // ---- one-time: W[r,512:2048] into registers (6x24 = 144 VGPR) ----
  float w[RPW][KC];
  const float* __restrict__ Wr = W + (size_t)r0 * LAY;
#pragma unroll
  for (int r = 0; r < RPW; ++r)
#pragma unroll
    for (int i = 0; i < KC; ++i)
      w[r][i] = Wr[(size_t)r * LAY + INN + ln + 64 * i];

  // ---- one-time: c_r = W[r,:512]@x (fully reduced; added AFTER lane-reduce) ----
  float c[RPW];
  {
    float xv[KX];
#pragma unroll
    for (int i = 0; i < KX; ++i) xv[i] = x[ln + 64 * i];
#pragma unroll
    for (int r = 0; r < RPW; ++r) {
      float cc = 0.f;
#pragma unroll
      for (int i = 0; i < KX; ++i)
        cc = fmaf(Wr[(size_t)r * LAY + ln + 64 * i], xv[i], cc);
#pragma unroll
      for (int o = 1; o < 64; o <<= 1) cc += __shfl_xor(cc, o, 64);
      c[r] = cc;
    }
  }

  // ---- bootstrap: act(1) = relu(c_r), tag 1 -> buf1; lane r stores row r
  //      (48B contiguous per wave -> coalesced, the R10 win) ----
  {
    float cv = c[0];                      // compile-time-indexed select
    cv = (ln == 1) ? c[1] : cv;
    cv = (ln == 2) ? c[2] : cv;
    cv = (ln == 3) ? c[3] : cv;
    cv = (ln == 4) ? c[4] : cv;
    cv = (ln == 5) ? c[5] : cv;
    if (ln < RPW)
      ag_store64(&buf1[r0 - INN + ln], packtag(fmaxf(cv, 0.f), 1u));
  }

  float myv[EPT];
  float inv = 0.f;
  for (int t = 1;; ++t) {
    if (t == NITER && blk != 0) return;   // non-0 blocks already stored tag 512
    uint64_t* rb = (t & 1) ? buf1 : buf0;

    // ---- poll act(t): batched reload, strided layout (tid + 256*j) =
    //      perfectly lane-coalesced 512B per load instruction ----
    uint64_t pv[EPT];
    for (;;) {
      bool ok = true;
#pragma unroll
      for (int j = 0; j < EPT; ++j)
        pv[j] = ag_load64(&rb[tid + TPB * j]);
#pragma unroll
      for (int j = 0; j < EPT; ++j)
        ok &= ((uint32_t)(pv[j] >> 32) == (uint32_t)t);
      if (ok) break;
    }

    // ---- stage to LDS + sum-of-squares of hidden part (j>=2 <=> e>=512) ----
    float ss = 0.f;
#pragma unroll
    for (int j = 0; j < EPT; ++j) {
      const float v = val_of(pv[j]);
      myv[j] = v;
      s_act[tid + TPB * j] = v;
      if (j >= 2) ss = fmaf(v, v, ss);
    }
#pragma unroll
    for (int o = 1; o < 64; o <<= 1) ss += __shfl_xor(ss, o, 64);
    if (ln == 0) s_red[wv] = ss;
    __syncthreads();                      // (A) poll consumed block-wide
    inv = 1.0f / fmaxf(sqrtf(s_red[0] + s_red[1] + s_red[2] + s_red[3]), EPS);

    if (t == NITER) break;                // only blk 0 reaches

    // ---- matvec: y = relu(c + W[:,y-region]@a + inv * W[:,hidden]@h) ----
    float aa[RPW], bb[RPW];
#pragma unroll
    for (int r = 0; r < RPW; ++r) { aa[r] = 0.f; bb[r] = 0.f; }
#pragma unroll
    for (int i = 0; i < 8; ++i) {         // dyn cols [0,512): y-region
      const float a = s_act[ln + 64 * i];
#pragma unroll
      for (int r = 0; r < RPW; ++r) aa[r] = fmaf(w[r][i], a, aa[r]);
    }
#pragma unroll
    for (int i = 8; i < KC; ++i) {        // dyn cols [512,1536): hidden
      const float a = s_act[ln + 64 * i];
#pragma unroll
      for (int r = 0; r < RPW; ++r) bb[r] = fmaf(w[r][i], a, bb[r]);
    }
    float y[RPW];
#pragma unroll
    for (int r = 0; r < RPW; ++r) y[r] = fmaf(inv, bb[r], aa[r]);
#pragma unroll
    for (int o = 1; o < 64; o <<= 1) {
#pragma unroll
      for (int r = 0; r < RPW; ++r) y[r] += __shfl_xor(y[r], o, 64);
    }
#pragma unroll
    for (int r = 0; r < RPW; ++r) y[r] = fmaxf(y[r] + c[r], 0.f);  // c AFTER reduce

    // ---- publish act(t+1) IMMEDIATELY (per wave, before barrier):
    //      lane r stores row r, coalesced 48B/wave ----
    {
      float yv = y[0];
      yv = (ln == 1) ? y[1] : yv;
      yv = (ln == 2) ? y[2] : yv;
      yv = (ln == 3) ? y[3] : yv;
      yv = (ln == 4) ? y[4] : yv;
      yv = (ln == 5) ? y[5] : yv;
      if (ln < RPW) {
        uint64_t* wbuf = ((t + 1) & 1) ? buf1 : buf0;
        ag_store64(&wbuf[r0 - INN + ln], packtag(yv, (uint32_t)(t + 1)));
      }
    }
    __syncthreads();                      // (B) WAR: s_act reads done before restage
  }

  // ---- blk 0: final output (hidden part normalized) ----
  out[tid]       = x[tid];
  out[tid + TPB] = x[tid + TPB];
#pragma unroll
  for (int j = 0; j < EPT; ++j)
    out[INN + tid + TPB * j] = (j < 2) ? myv[j] : myv[j] * inv;
}
} // namespace

extern "C" void kernel_launch(void* const* d_in, const int* in_sizes, int n_in,
                              void* d_out, int out_size, void* d_ws, size_t ws_size,
                              hipStream_t stream) {
  const float* x = (const float*)d_in[0];
  // d_in[1] (y) only enters the reference as zeros_like -> unused.
  const float* W = (const float*)d_in[2];
  float* out = (float*)d_out;

  uint64_t* buf0 = (uint64_t*)d_ws;
  uint64_t* buf1 = buf0 + DYN;

  // Invalidate stale tags (0xFFFFFFFF matches no t in 1..512) — needed on the
  // first call and between graph replays (harness does not re-poison d_ws).
  hipMemsetAsync(d_ws, 0xFF, (size_t)2 * DYN * sizeof(uint64_t), stream);

  bm_tag<<<dim3(NBLK), dim3(TPB), 0, stream>>>(x, W, buf0, buf1, out);
}

// Round 14
// 1180.625 us; speedup vs baseline: 1.2889x; 1.1011x over previous
//
#include <hip/hip_runtime.h>
#include <math.h>
#include <stdint.h>

namespace {
constexpr int INN   = 512;          // visible rows: act[:512] == x always
constexpr int LAY   = 2048;
constexpr int DYN   = LAY - INN;    // 1536 dynamic elements act[512..2048)
constexpr int NITER = 512;
constexpr int NBLK  = 64;
constexpr int TPB   = 256;          // 4 waves
constexpr int WVS   = TPB / 64;     // 4
constexpr int RPW   = 6;            // rows per wave
constexpr int RPB   = WVS * RPW;    // 24 rows/block; 64*24 = 1536
constexpr int KC    = DYN / 64;     // 24 dynamic k-chunks per lane
constexpr int KX    = INN / 64;     // 8 x-col k-chunks (precomputed)
constexpr int EPT   = DYN / TPB;    // 6 polled elements per thread
constexpr float EPS = 1e-12f;

__device__ __forceinline__ uint64_t packtag(float v, uint32_t tag) {
  union { float f; uint32_t u; } c; c.f = v;
  return (uint64_t)c.u | ((uint64_t)tag << 32);
}
__device__ __forceinline__ float val_of(uint64_t p) {
  union { uint32_t u; float f; } c; c.u = (uint32_t)p; return c.f;
}
// Proven store medium (R2..R12, absmax 0.0): agent-scope UC, HBM-backed.
__device__ __forceinline__ void ag_store64(uint64_t* p, uint64_t v) {
  __hip_atomic_store(p, v, __ATOMIC_RELAXED, __HIP_MEMORY_SCOPE_AGENT);
}

// Issue 6 UC poll loads (strided tid+256j layout = 512B lane-coalesced per
// instruction, the R10-proven pattern; sc0 sc1 = same UC path, R11-proven
// correct). No waitcnt here — counted wait comes separately.
#define ISSUE6(P0, P1, P2, A0, A1, A2, A3, A4, A5)                         \
  asm volatile(                                                            \
      "global_load_dwordx2 %0, %6, off sc0 sc1\n\t"                        \
      "global_load_dwordx2 %1, %6, off offset:2048 sc0 sc1\n\t"            \
      "global_load_dwordx2 %2, %7, off sc0 sc1\n\t"                        \
      "global_load_dwordx2 %3, %7, off offset:2048 sc0 sc1\n\t"            \
      "global_load_dwordx2 %4, %8, off sc0 sc1\n\t"                        \
      "global_load_dwordx2 %5, %8, off offset:2048 sc0 sc1"                \
      : "=&v"(A0), "=&v"(A1), "=&v"(A2), "=&v"(A3), "=&v"(A4), "=&v"(A5)   \
      : "v"(P0), "v"(P1), "v"(P2)                                          \
      : "memory")

// Counted wait: oldest 6 of 12 outstanding complete (vmcnt FIFO semantics,
// m135-verified). The checked registers are "+v" operands so the compiler
// cannot hoist their use above the wait (rule-#18 fence).
#define WAIT6(A0, A1, A2, A3, A4, A5)                                      \
  asm volatile("s_waitcnt vmcnt(6)"                                        \
               : "+v"(A0), "+v"(A1), "+v"(A2), "+v"(A3), "+v"(A4), "+v"(A5)\
               :: "memory")

// R12 champion (1300 us, absmax 0.0) + software-pipelined poll: two 6-load
// sets alternate in flight; each check runs on data exactly ~1 RTT old
// instead of up to ~2 RTT (serial-pass rhythm). Stale or torn-free reads are
// harmless: every 8B word self-validates via its tag. Protocol unchanged:
// a block stores tag t+1 only after block-wide consumption of tag t
// (sync A between poll and any parity-clobbering store path), so tag t+2
// stores imply every block consumed t. Store-before-sync-B safety as in R12.
__global__ __launch_bounds__(TPB) void bm_tag(
    const float* __restrict__ x, const float* __restrict__ W,
    uint64_t* __restrict__ buf0, uint64_t* __restrict__ buf1,
    float* __restrict__ out) {
  __shared__ float s_act[DYN];
  __shared__ float s_red[WVS];
  const int tid = threadIdx.x;
  const int wv  = tid >> 6;
  const int ln  = tid & 63;
  const int blk = blockIdx.x;
  const int r0  = INN + blk * RPB + wv * RPW;   // this wave's 6 rows

  // ---- one-time: W[r,512:2048] into registers (6x24 = 144 regs) ----
  float w[RPW][KC];
  const float* __restrict__ Wr = W + (size_t)r0 * LAY;
#pragma unroll
  for (int r = 0; r < RPW; ++r)
#pragma unroll
    for (int i = 0; i < KC; ++i)
      w[r][i] = Wr[(size_t)r * LAY + INN + ln + 64 * i];

  // ---- one-time: c_r = W[r,:512]@x (fully reduced; added AFTER lane-reduce) ----
  float c[RPW];
  {
    float xv[KX];
#pragma unroll
    for (int i = 0; i < KX; ++i) xv[i] = x[ln + 64 * i];
#pragma unroll
    for (int r = 0; r < RPW; ++r) {
      float cc = 0.f;
#pragma unroll
      for (int i = 0; i < KX; ++i)
        cc = fmaf(Wr[(size_t)r * LAY + ln + 64 * i], xv[i], cc);
#pragma unroll
      for (int o = 1; o < 64; o <<= 1) cc += __shfl_xor(cc, o, 64);
      c[r] = cc;
    }
  }

  // ---- bootstrap: act(1) = relu(c_r), tag 1 -> buf1; lane r stores row r ----
  {
    float cv = c[0];
    cv = (ln == 1) ? c[1] : cv;
    cv = (ln == 2) ? c[2] : cv;
    cv = (ln == 3) ? c[3] : cv;
    cv = (ln == 4) ? c[4] : cv;
    cv = (ln == 5) ? c[5] : cv;
    if (ln < RPW)
      ag_store64(&buf1[r0 - INN + ln], packtag(fmaxf(cv, 0.f), 1u));
  }

  float myv[EPT];
  float inv = 0.f;
  for (int t = 1;; ++t) {
    if (t == NITER && blk != 0) return;   // non-0 blocks already stored tag 512
    uint64_t* rb = (t & 1) ? buf1 : buf0;
    const uint64_t* p0 = rb + tid;
    const uint64_t* p1 = rb + tid + 512;
    const uint64_t* p2 = rb + tid + 1024;

    // ---- pipelined poll: sets A/B alternate; check age ~= 1 RTT ----
    {
      uint64_t a0, a1, a2, a3, a4, a5, b0, b1, b2, b3, b4, b5;
      const uint32_t tt = (uint32_t)t;
      asm volatile("s_waitcnt vmcnt(0)" ::: "memory");  // quiesce prior leftovers
      ISSUE6(p0, p1, p2, a0, a1, a2, a3, a4, a5);
      ISSUE6(p0, p1, p2, b0, b1, b2, b3, b4, b5);
      for (;;) {
        WAIT6(a0, a1, a2, a3, a4, a5);                  // A complete, B in flight
        if ((uint32_t)(a0 >> 32) == tt && (uint32_t)(a1 >> 32) == tt &&
            (uint32_t)(a2 >> 32) == tt && (uint32_t)(a3 >> 32) == tt &&
            (uint32_t)(a4 >> 32) == tt && (uint32_t)(a5 >> 32) == tt) {
          myv[0] = val_of(a0); myv[1] = val_of(a1); myv[2] = val_of(a2);
          myv[3] = val_of(a3); myv[4] = val_of(a4); myv[5] = val_of(a5);
          break;
        }
        ISSUE6(p0, p1, p2, a0, a1, a2, a3, a4, a5);     // reissue A (12 in flight)
        WAIT6(b0, b1, b2, b3, b4, b5);                  // B complete, A in flight
        if ((uint32_t)(b0 >> 32) == tt && (uint32_t)(b1 >> 32) == tt &&
            (uint32_t)(b2 >> 32) == tt && (uint32_t)(b3 >> 32) == tt &&
            (uint32_t)(b4 >> 32) == tt && (uint32_t)(b5 >> 32) == tt) {
          myv[0] = val_of(b0); myv[1] = val_of(b1); myv[2] = val_of(b2);
          myv[3] = val_of(b3); myv[4] = val_of(b4); myv[5] = val_of(b5);
          break;
        }
        ISSUE6(p0, p1, p2, b0, b1, b2, b3, b4, b5);
      }
      // one stale set may remain in flight: harmless (tag-validated medium;
      // quiesced by the vmcnt(0) at the next poll's start).
    }

    // ---- stage to LDS + sum-of-squares of hidden part (j>=2 <=> e>=512) ----
    float ss = 0.f;
#pragma unroll
    for (int j = 0; j < EPT; ++j) {
      s_act[tid + TPB * j] = myv[j];
      if (j >= 2) ss = fmaf(myv[j], myv[j], ss);
    }
#pragma unroll
    for (int o = 1; o < 64; o <<= 1) ss += __shfl_xor(ss, o, 64);
    if (ln == 0) s_red[wv] = ss;
    __syncthreads();                      // (A) poll consumed block-wide
    inv = 1.0f / fmaxf(sqrtf(s_red[0] + s_red[1] + s_red[2] + s_red[3]), EPS);

    if (t == NITER) break;                // only blk 0 reaches

    // ---- matvec: y = relu(c + W[:,y-region]@a + inv * W[:,hidden]@h) ----
    float aa[RPW], bb[RPW];
#pragma unroll
    for (int r = 0; r < RPW; ++r) { aa[r] = 0.f; bb[r] = 0.f; }
#pragma unroll
    for (int i = 0; i < 8; ++i) {         // dyn cols [0,512): y-region
      const float a = s_act[ln + 64 * i];
#pragma unroll
      for (int r = 0; r < RPW; ++r) aa[r] = fmaf(w[r][i], a, aa[r]);
    }
#pragma unroll
    for (int i = 8; i < KC; ++i) {        // dyn cols [512,1536): hidden
      const float a = s_act[ln + 64 * i];
#pragma unroll
      for (int r = 0; r < RPW; ++r) bb[r] = fmaf(w[r][i], a, bb[r]);
    }
    float y[RPW];
#pragma unroll
    for (int r = 0; r < RPW; ++r) y[r] = fmaf(inv, bb[r], aa[r]);
#pragma unroll
    for (int o = 1; o < 64; o <<= 1) {
#pragma unroll
      for (int r = 0; r < RPW; ++r) y[r] += __shfl_xor(y[r], o, 64);
    }
#pragma unroll
    for (int r = 0; r < RPW; ++r) y[r] = fmaxf(y[r] + c[r], 0.f);  // c AFTER reduce

    // ---- publish act(t+1) immediately (R12 win): lane r stores row r ----
    {
      float yv = y[0];
      yv = (ln == 1) ? y[1] : yv;
      yv = (ln == 2) ? y[2] : yv;
      yv = (ln == 3) ? y[3] : yv;
      yv = (ln == 4) ? y[4] : yv;
      yv = (ln == 5) ? y[5] : yv;
      if (ln < RPW) {
        uint64_t* wbuf = ((t + 1) & 1) ? buf1 : buf0;
        ag_store64(&wbuf[r0 - INN + ln], packtag(yv, (uint32_t)(t + 1)));
      }
    }
    __syncthreads();                      // (B) WAR: s_act reads done before restage
  }

  // ---- blk 0: final output (hidden part normalized) ----
  out[tid]       = x[tid];
  out[tid + TPB] = x[tid + TPB];
#pragma unroll
  for (int j = 0; j < EPT; ++j)
    out[INN + tid + TPB * j] = (j < 2) ? myv[j] : myv[j] * inv;
}
} // namespace

extern "C" void kernel_launch(void* const* d_in, const int* in_sizes, int n_in,
                              void* d_out, int out_size, void* d_ws, size_t ws_size,
                              hipStream_t stream) {
  const float* x = (const float*)d_in[0];
  // d_in[1] (y) only enters the reference as zeros_like -> unused.
  const float* W = (const float*)d_in[2];
  float* out = (float*)d_out;

  uint64_t* buf0 = (uint64_t*)d_ws;
  uint64_t* buf1 = buf0 + DYN;

  // Invalidate stale tags (0xFFFFFFFF matches no t in 1..512) — needed on the
  // first call and between graph replays (harness does not re-poison d_ws).
  hipMemsetAsync(d_ws, 0xFF, (size_t)2 * DYN * sizeof(uint64_t), stream);

  bm_tag<<<dim3(NBLK), dim3(TPB), 0, stream>>>(x, W, buf0, buf1, out);
}